// Round 1
// baseline (25502.394 us; speedup 1.0000x reference)
//
#include <hip/hip_runtime.h>
#include <math.h>

#define H   512
#define B   512
#define T   512
#define G4  2048   // 4*H
#define TGT 28

#define BT  32     // batch tile
#define CT  32     // h-column tile per WG (each col needs 4 gate rows)
#define KC  64     // K chunk
#define KP  68     // padded LDS stride (68 floats = 17 float4 -> odd -> no b128 conflicts)

// ws layout (floats):
//   h0   : [0, 262144)
//   h1   : [262144, 524288)
//   c    : [524288, 786432)
//   bias : [786432, 788480)   b_ih + b_hh folded
#define WS_H0   0
#define WS_H1   262144
#define WS_C    524288
#define WS_BIAS 786432
#define WS_TOT  788480

__global__ __launch_bounds__(256) void init_kernel(float* __restrict__ ws,
                                                   const float* __restrict__ bih,
                                                   const float* __restrict__ bhh) {
    int idx = blockIdx.x * 256 + threadIdx.x;
    if (idx < WS_BIAS) {
        ws[idx] = 0.0f;                       // zero h0, h1, c
    } else if (idx < WS_TOT) {
        int g = idx - WS_BIAS;
        ws[idx] = bih[g] + bhh[g];
    }
}

__global__ __launch_bounds__(256) void lstm_step(const float* __restrict__ Whh,
                                                 const float* __restrict__ Wih,
                                                 const float* __restrict__ bias,
                                                 const float* __restrict__ seq,
                                                 const float* __restrict__ h_in,
                                                 float* __restrict__ h_out,
                                                 float* __restrict__ c_buf,
                                                 int t) {
    __shared__ __align__(16) float hs[BT][KP];        // h tile   [32][68]
    __shared__ __align__(16) float wsm[4][CT][KP];    // W tiles  [gate][k_local][68]

    const int tid = threadIdx.x;
    const int k_l = tid & 31;        // h-column within tile
    const int bq  = tid >> 5;        // 0..7, owns 4 consecutive b rows
    const int b0  = blockIdx.x * BT;
    const int c0  = blockIdx.y * CT;

    float acc[4][4];                 // [b_sub][gate]
#pragma unroll
    for (int j = 0; j < 4; ++j)
#pragma unroll
        for (int q = 0; q < 4; ++q) acc[j][q] = 0.0f;

    for (int kc = 0; kc < H; kc += KC) {
        // stage h tile: 32 rows x 64 cols = 512 float4
#pragma unroll
        for (int i = 0; i < 2; ++i) {
            int idx = tid + i * 256;          // 0..511
            int row = idx >> 4;               // 0..31
            int c4  = idx & 15;
            float4 v = *(const float4*)(h_in + (size_t)(b0 + row) * H + kc + c4 * 4);
            *(float4*)&hs[row][c4 * 4] = v;
        }
        // stage W tiles: 4 gates x 32 rows x 64 cols = 2048 float4
#pragma unroll
        for (int i = 0; i < 8; ++i) {
            int idx = tid + i * 256;          // 0..2047
            int q   = idx >> 9;               // 0..3
            int rem = idx & 511;
            int r   = rem >> 4;               // 0..31
            int c4  = rem & 15;
            float4 v = *(const float4*)(Whh + (size_t)(q * H + c0 + r) * H + kc + c4 * 4);
            *(float4*)&wsm[q][r][c4 * 4] = v;
        }
        __syncthreads();

#pragma unroll
        for (int kk = 0; kk < KC; kk += 4) {
            float4 a[4], w[4];
#pragma unroll
            for (int j = 0; j < 4; ++j) a[j] = *(const float4*)&hs[bq * 4 + j][kk];
#pragma unroll
            for (int q = 0; q < 4; ++q) w[q] = *(const float4*)&wsm[q][k_l][kk];
#pragma unroll
            for (int j = 0; j < 4; ++j)
#pragma unroll
                for (int q = 0; q < 4; ++q)
                    acc[j][q] += a[j].x * w[q].x + a[j].y * w[q].y +
                                 a[j].z * w[q].z + a[j].w * w[q].w;
        }
        __syncthreads();
    }

    // LSTM cell update for (b0+bq*4+j, c0+k_l)
    const int k = c0 + k_l;
#pragma unroll
    for (int j = 0; j < 4; ++j) {
        int b = b0 + bq * 4 + j;
        float sv = seq[(size_t)b * T + t];
        float pre[4];
#pragma unroll
        for (int q = 0; q < 4; ++q) {
            int g = q * H + k;
            pre[q] = acc[j][q] + sv * Wih[g] + bias[g];
        }
        float ig = 1.0f / (1.0f + expf(-pre[0]));
        float fg = 1.0f / (1.0f + expf(-pre[1]));
        float gg = tanhf(pre[2]);
        float og = 1.0f / (1.0f + expf(-pre[3]));
        size_t ci = (size_t)b * H + k;
        float cnew = fg * c_buf[ci] + ig * gg;
        c_buf[ci] = cnew;
        h_out[ci] = og * tanhf(cnew);
    }
}

__global__ __launch_bounds__(256) void head_kernel(const float* __restrict__ h,
                                                   const float* __restrict__ fc1w,
                                                   const float* __restrict__ fc1b,
                                                   const float* __restrict__ fc2w,
                                                   const float* __restrict__ fc2b,
                                                   float* __restrict__ out) {
    const int b = blockIdx.x;
    const int tid = threadIdx.x;
    __shared__ __align__(16) float hb[H];
    __shared__ float z[256];

    *(float4*)&hb[tid * 2] = ((tid & 1) == 0)
        ? *(const float4*)(h + (size_t)b * H + tid * 2)
        : *(const float4*)(h + (size_t)b * H + tid * 2 + 2 - 2);
    // simpler & surely correct: scalar loads (overwrite above pattern)
    hb[tid]       = h[(size_t)b * H + tid];
    hb[tid + 256] = h[(size_t)b * H + tid + 256];
    __syncthreads();

    // z = relu(h @ fc1_w^T + fc1_b), fc1_w: [256,512]
    float acc = fc1b[tid];
    const float4* wr = (const float4*)(fc1w + (size_t)tid * H);
    const float4* hr = (const float4*)hb;
#pragma unroll 4
    for (int kk = 0; kk < H / 4; ++kk) {
        float4 wv = wr[kk], hv = hr[kk];
        acc += wv.x * hv.x + wv.y * hv.y + wv.z * hv.z + wv.w * hv.w;
    }
    z[tid] = fmaxf(acc, 0.0f);
    __syncthreads();

    // out = z @ fc2_w^T + fc2_b, fc2_w: [28,256]
    if (tid < TGT) {
        float a = fc2b[tid];
        const float* w2 = fc2w + (size_t)tid * 256;
#pragma unroll 8
        for (int j = 0; j < 256; ++j) a += z[j] * w2[j];
        out[(size_t)b * TGT + tid] = a;
    }
}

extern "C" void kernel_launch(void* const* d_in, const int* in_sizes, int n_in,
                              void* d_out, int out_size, void* d_ws, size_t ws_size,
                              hipStream_t stream) {
    const float* seq  = (const float*)d_in[0];
    const float* Wih  = (const float*)d_in[1];
    const float* Whh  = (const float*)d_in[2];
    const float* bih  = (const float*)d_in[3];
    const float* bhh  = (const float*)d_in[4];
    const float* fc1w = (const float*)d_in[5];
    const float* fc1b = (const float*)d_in[6];
    const float* fc2w = (const float*)d_in[7];
    const float* fc2b = (const float*)d_in[8];
    float* out = (float*)d_out;
    float* ws  = (float*)d_ws;

    float* h0   = ws + WS_H0;
    float* h1   = ws + WS_H1;
    float* c    = ws + WS_C;
    float* bias = ws + WS_BIAS;

    init_kernel<<<(WS_TOT + 255) / 256, 256, 0, stream>>>(ws, bih, bhh);

    for (int t = 0; t < T; ++t) {
        const float* hin = (t & 1) ? h1 : h0;
        float*       hout = (t & 1) ? h0 : h1;
        lstm_step<<<dim3(B / BT, H / CT), 256, 0, stream>>>(Whh, Wih, bias, seq,
                                                            hin, hout, c, t);
    }
    // T=512 even -> final h lives in h0
    head_kernel<<<B, 256, 0, stream>>>(h0, fc1w, fc1b, fc2w, fc2b, out);
}

// Round 2
// 6578.086 us; speedup vs baseline: 3.8769x; 3.8769x over previous
//
#include <hip/hip_runtime.h>
#include <math.h>

#define H   512
#define B   512
#define T   512
#define TGT 28

typedef __bf16 bf16x8 __attribute__((ext_vector_type(8)));
typedef float  f32x4  __attribute__((ext_vector_type(4)));
typedef unsigned short u16;

// ws byte offsets
#define OFF_WPH  0x000000u  // Wpack_hi 2MB (frag-linear bf16)
#define OFF_WPL  0x200000u  // Wpack_lo 2MB
#define OFF_HHI0 0x400000u  // 512KB  h hi, buffer 0
#define OFF_HLO0 0x480000u  // 512KB  h lo, buffer 0
#define OFF_C    0x500000u  // 1MB    c state fp32
#define OFF_HHI1 0x600000u  // 512KB  h hi, buffer 1
#define OFF_HLO1 0x680000u  // 512KB  h lo, buffer 1
#define OFF_BIAS 0x700000u  // 8KB    b_ih + b_hh fp32
// total 0x702000 (~7.01 MB)

__device__ inline u16 f2bf(float x) {
    unsigned u = __builtin_bit_cast(unsigned, x);
    u += 0x7FFFu + ((u >> 16) & 1u);          // round-to-nearest-even
    return (u16)(u >> 16);
}
__device__ inline float bf2f(u16 h) {
    unsigned u = ((unsigned)h) << 16;
    return __builtin_bit_cast(float, u);
}

// ---------------------------------------------------------------------------
// Pack W_hh into fragment-linear bf16 hi/lo.
// Frag id: ((by*4 + q)*16 + S)*64 + lane ; each entry 8 contiguous k (16B).
// lane: g = q*512 + by*16 + (lane&15) ; k = S*32 + (lane>>4)*8
// ---------------------------------------------------------------------------
__global__ __launch_bounds__(256) void init_pack(const float* __restrict__ Whh,
                                                 u16* __restrict__ wph,
                                                 u16* __restrict__ wpl) {
    int idx = blockIdx.x * 256 + threadIdx.x;   // [0, 131072)
    int l  = idx & 63;
    int S  = (idx >> 6) & 15;
    int q  = (idx >> 10) & 3;
    int by = idx >> 12;
    int g  = q * 512 + by * 16 + (l & 15);
    int k  = S * 32 + ((l >> 4) * 8);
    const float* src = Whh + (size_t)g * H + k;
    __align__(16) u16 hi8[8];
    __align__(16) u16 lo8[8];
#pragma unroll
    for (int j = 0; j < 8; ++j) {
        float w = src[j];
        u16 hb = f2bf(w);
        hi8[j] = hb;
        lo8[j] = f2bf(w - bf2f(hb));
    }
    *(uint4*)(wph + (size_t)idx * 8) = *(const uint4*)hi8;
    *(uint4*)(wpl + (size_t)idx * 8) = *(const uint4*)lo8;
}

// zero h0 hi/lo + c (2MB = 524288 dwords starting at OFF_HHI0), fill bias
__global__ __launch_bounds__(256) void init_state(unsigned* __restrict__ zbase,
                                                  float* __restrict__ bias,
                                                  const float* __restrict__ bih,
                                                  const float* __restrict__ bhh) {
    int idx = blockIdx.x * 256 + threadIdx.x;   // [0, 526336)
    if (idx < 524288) {
        zbase[idx] = 0u;
    } else {
        int g = idx - 524288;                   // [0, 2048)
        bias[g] = bih[g] + bhh[g];
    }
}

// ---------------------------------------------------------------------------
// One LSTM timestep. Grid (8,32): bx -> 64-batch tile, by -> 16 h-cols.
// 512 threads = 8 waves: (mt, nt, kh). Wave tile 32b x 32g, K-split 2x256.
// n-dim of WG tile = 4 gates x 16 cols: nsub picks gate q = nt*2+nsub.
// bf16x3: acc += Ahi*Bhi + Ahi*Blo + Alo*Bhi  (fp32 accum).
// ---------------------------------------------------------------------------
__global__ __launch_bounds__(512, 2) void lstm_step(
    const u16* __restrict__ wph, const u16* __restrict__ wpl,
    const u16* __restrict__ hhi_in, const u16* __restrict__ hlo_in,
    u16* __restrict__ hhi_out, u16* __restrict__ hlo_out,
    float* __restrict__ c_buf, const float* __restrict__ bias,
    const float* __restrict__ Wih, const float* __restrict__ seq, int t)
{
    const int tid  = threadIdx.x;
    const int l    = tid & 63;
    const int wave = tid >> 6;
    const int mt = wave & 1, nt = (wave >> 1) & 1, kh = wave >> 2;
    const int bx = blockIdx.x, by = blockIdx.y;

    __shared__ float gates[64][65];

    f32x4 acc[2][2] = {};

    // A: h rows, row-major K. msub adds 16 rows.
    const int arow0 = (bx * 64 + mt * 32 + (l & 15)) * H;
    const int arow1 = arow0 + 16 * H;
    const int kbase = kh * 256 + ((l >> 4) * 8);
    // B: frag-linear packed W. S = kh*8 + s.
    const size_t bb0 = ((size_t)((by * 4 + nt * 2 + 0) * 16 + kh * 8) * 64 + l) * 8;
    const size_t bb1 = ((size_t)((by * 4 + nt * 2 + 1) * 16 + kh * 8) * 64 + l) * 8;

#pragma unroll
    for (int s = 0; s < 8; ++s) {
        const int ka = kbase + s * 32;
        const size_t bs = (size_t)s * 64 * 8;
        bf16x8 a0h = *(const bf16x8*)(hhi_in + arow0 + ka);
        bf16x8 a1h = *(const bf16x8*)(hhi_in + arow1 + ka);
        bf16x8 a0l = *(const bf16x8*)(hlo_in + arow0 + ka);
        bf16x8 a1l = *(const bf16x8*)(hlo_in + arow1 + ka);
        bf16x8 b0h = *(const bf16x8*)(wph + bb0 + bs);
        bf16x8 b1h = *(const bf16x8*)(wph + bb1 + bs);
        bf16x8 b0l = *(const bf16x8*)(wpl + bb0 + bs);
        bf16x8 b1l = *(const bf16x8*)(wpl + bb1 + bs);

        acc[0][0] = __builtin_amdgcn_mfma_f32_16x16x32_bf16(a0h, b0h, acc[0][0], 0, 0, 0);
        acc[0][1] = __builtin_amdgcn_mfma_f32_16x16x32_bf16(a0h, b1h, acc[0][1], 0, 0, 0);
        acc[1][0] = __builtin_amdgcn_mfma_f32_16x16x32_bf16(a1h, b0h, acc[1][0], 0, 0, 0);
        acc[1][1] = __builtin_amdgcn_mfma_f32_16x16x32_bf16(a1h, b1h, acc[1][1], 0, 0, 0);
        acc[0][0] = __builtin_amdgcn_mfma_f32_16x16x32_bf16(a0h, b0l, acc[0][0], 0, 0, 0);
        acc[0][1] = __builtin_amdgcn_mfma_f32_16x16x32_bf16(a0h, b1l, acc[0][1], 0, 0, 0);
        acc[1][0] = __builtin_amdgcn_mfma_f32_16x16x32_bf16(a1h, b0l, acc[1][0], 0, 0, 0);
        acc[1][1] = __builtin_amdgcn_mfma_f32_16x16x32_bf16(a1h, b1l, acc[1][1], 0, 0, 0);
        acc[0][0] = __builtin_amdgcn_mfma_f32_16x16x32_bf16(a0l, b0h, acc[0][0], 0, 0, 0);
        acc[0][1] = __builtin_amdgcn_mfma_f32_16x16x32_bf16(a0l, b1h, acc[0][1], 0, 0, 0);
        acc[1][0] = __builtin_amdgcn_mfma_f32_16x16x32_bf16(a1l, b0h, acc[1][0], 0, 0, 0);
        acc[1][1] = __builtin_amdgcn_mfma_f32_16x16x32_bf16(a1l, b1h, acc[1][1], 0, 0, 0);
    }

    // K-split reduction + gate regroup through LDS.
    // D layout (verified): col = lane&15, row = (lane>>4)*4 + reg.
    if (kh == 1) {
#pragma unroll
        for (int ms = 0; ms < 2; ++ms)
#pragma unroll
            for (int ns = 0; ns < 2; ++ns)
#pragma unroll
                for (int r = 0; r < 4; ++r) {
                    int m = mt * 32 + ms * 16 + (l >> 4) * 4 + r;
                    int n = nt * 32 + ns * 16 + (l & 15);
                    gates[m][n] = acc[ms][ns][r];
                }
    }
    __syncthreads();
    if (kh == 0) {
#pragma unroll
        for (int ms = 0; ms < 2; ++ms)
#pragma unroll
            for (int ns = 0; ns < 2; ++ns)
#pragma unroll
                for (int r = 0; r < 4; ++r) {
                    int m = mt * 32 + ms * 16 + (l >> 4) * 4 + r;
                    int n = nt * 32 + ns * 16 + (l & 15);
                    gates[m][n] += acc[ms][ns][r];
                }
    }
    __syncthreads();

    // Cell phase: 1024 cells (64b x 16cols), 2 per thread.
    const int cc = tid & 15;
    const int m0 = tid >> 4;          // 0..31
    const int kcol = by * 16 + cc;
#pragma unroll
    for (int mm = 0; mm < 2; ++mm) {
        int m = m0 + mm * 32;
        int b = bx * 64 + m;
        float sv = seq[(size_t)b * T + t];
        float pre[4];
#pragma unroll
        for (int q = 0; q < 4; ++q) {
            int g = q * 512 + kcol;
            pre[q] = gates[m][q * 16 + cc] + sv * Wih[g] + bias[g];
        }
        float ig = 1.0f / (1.0f + expf(-pre[0]));
        float fg = 1.0f / (1.0f + expf(-pre[1]));
        float gg = tanhf(pre[2]);
        float og = 1.0f / (1.0f + expf(-pre[3]));
        size_t ci = (size_t)b * H + kcol;
        float cn = fg * c_buf[ci] + ig * gg;
        c_buf[ci] = cn;
        float hv = og * tanhf(cn);
        u16 hb = f2bf(hv);
        hhi_out[ci] = hb;
        hlo_out[ci] = f2bf(hv - bf2f(hb));
    }
}

// ---------------------------------------------------------------------------
// MLP head: h (reconstructed hi+lo) -> fc1+ReLU -> fc2
// ---------------------------------------------------------------------------
__global__ __launch_bounds__(256) void head_kernel(const u16* __restrict__ hhi,
                                                   const u16* __restrict__ hlo,
                                                   const float* __restrict__ fc1w,
                                                   const float* __restrict__ fc1b,
                                                   const float* __restrict__ fc2w,
                                                   const float* __restrict__ fc2b,
                                                   float* __restrict__ out) {
    const int b = blockIdx.x;
    const int tid = threadIdx.x;
    __shared__ __align__(16) float hb[H];
    __shared__ float z[256];

    hb[tid]       = bf2f(hhi[(size_t)b * H + tid])       + bf2f(hlo[(size_t)b * H + tid]);
    hb[tid + 256] = bf2f(hhi[(size_t)b * H + tid + 256]) + bf2f(hlo[(size_t)b * H + tid + 256]);
    __syncthreads();

    float acc = fc1b[tid];
    const float4* wr = (const float4*)(fc1w + (size_t)tid * H);
    const float4* hr = (const float4*)hb;
#pragma unroll 4
    for (int kk = 0; kk < H / 4; ++kk) {
        float4 wv = wr[kk], hv = hr[kk];
        acc += wv.x * hv.x + wv.y * hv.y + wv.z * hv.z + wv.w * hv.w;
    }
    z[tid] = fmaxf(acc, 0.0f);
    __syncthreads();

    if (tid < TGT) {
        float a = fc2b[tid];
        const float* w2 = fc2w + (size_t)tid * 256;
#pragma unroll 8
        for (int j = 0; j < 256; ++j) a += z[j] * w2[j];
        out[(size_t)b * TGT + tid] = a;
    }
}

extern "C" void kernel_launch(void* const* d_in, const int* in_sizes, int n_in,
                              void* d_out, int out_size, void* d_ws, size_t ws_size,
                              hipStream_t stream) {
    const float* seq  = (const float*)d_in[0];
    const float* Wih  = (const float*)d_in[1];
    const float* Whh  = (const float*)d_in[2];
    const float* bih  = (const float*)d_in[3];
    const float* bhh  = (const float*)d_in[4];
    const float* fc1w = (const float*)d_in[5];
    const float* fc1b = (const float*)d_in[6];
    const float* fc2w = (const float*)d_in[7];
    const float* fc2b = (const float*)d_in[8];
    float* out = (float*)d_out;

    char* wsb = (char*)d_ws;
    u16*   wph  = (u16*)(wsb + OFF_WPH);
    u16*   wpl  = (u16*)(wsb + OFF_WPL);
    u16*   hhi0 = (u16*)(wsb + OFF_HHI0);
    u16*   hlo0 = (u16*)(wsb + OFF_HLO0);
    u16*   hhi1 = (u16*)(wsb + OFF_HHI1);
    u16*   hlo1 = (u16*)(wsb + OFF_HLO1);
    float* cbuf = (float*)(wsb + OFF_C);
    float* bias = (float*)(wsb + OFF_BIAS);

    init_pack<<<512, 256, 0, stream>>>(Whh, wph, wpl);
    init_state<<<2056, 256, 0, stream>>>((unsigned*)(wsb + OFF_HHI0), bias, bih, bhh);

    for (int t = 0; t < T; ++t) {
        const u16* ihi = (t & 1) ? hhi1 : hhi0;
        const u16* ilo = (t & 1) ? hlo1 : hlo0;
        u16* ohi = (t & 1) ? hhi0 : hhi1;
        u16* olo = (t & 1) ? hlo0 : hlo1;
        lstm_step<<<dim3(8, 32), 512, 0, stream>>>(wph, wpl, ihi, ilo, ohi, olo,
                                                   cbuf, bias, Wih, seq, t);
    }
    // T even -> final h in buffer 0
    head_kernel<<<B, 256, 0, stream>>>(hhi0, hlo0, fc1w, fc1b, fc2w, fc2b, out);
}